// Round 4
// baseline (2295.861 us; speedup 1.0000x reference)
//
#include <hip/hip_runtime.h>

typedef unsigned short u16;

// ---- problem constants ----
#define BB 256
#define LL 200
#define NN 512
#define DD 64
#define HH 128

// d_out element offsets (fp32 elements)
#define MU_OFF   26214400
#define LV_OFF   26230784
#define ZT_OFF   26247168
#define ZD_OFF   29523968

typedef __attribute__((ext_vector_type(8))) short bf8v;   // 8 bf16 (4 VGPRs) MFMA frag
typedef __attribute__((ext_vector_type(4))) short bf4v;   // 4 bf16 (8B)
typedef __attribute__((ext_vector_type(4))) float f32x4;  // MFMA accum

__device__ __forceinline__ float bf2f(u16 u) {
    union { unsigned int i; float f; } v; v.i = ((unsigned int)u) << 16; return v.f;
}
__device__ __forceinline__ u16 f2bf(float f) {
    union { float f; unsigned int u; } v; v.f = f;
    unsigned int r = v.u + 0x7FFFu + ((v.u >> 16) & 1u);   // RNE
    return (u16)(r >> 16);
}
// Runtime input-dtype probe: tvec[199] as bf16 reads ~1.99 if inputs are
// bf16; if fp32, u16[199] is the high half of float tvec[99] (~0.988).
__device__ __forceinline__ bool detect_f32(const void* tvec) {
    float v = bf2f(((const u16*)tvec)[199]);
    return !(v > 1.5f && v < 2.5f);
}
__device__ __forceinline__ float loadf(const void* p, long idx, bool f32m) {
    return f32m ? ((const float*)p)[idx] : bf2f(((const u16*)p)[idx]);
}
__device__ __forceinline__ bf4v pack4bf(float a, float b, float c, float d) {
    bf4v r;
    r.x = (short)f2bf(a); r.y = (short)f2bf(b);
    r.z = (short)f2bf(c); r.w = (short)f2bf(d);
    return r;
}
// HW packed f32->2xbf16 (RNE). No builtin on gfx950 (m240) — inline asm.
__device__ __forceinline__ unsigned int cvtpk2(float a, float b) {
    unsigned int r;
    asm("v_cvt_pk_bf16_f32 %0, %1, %2" : "=v"(r) : "v"(a), "v"(b));
    return r;
}
__device__ __forceinline__ float silu_f(float v) {
    return v * __builtin_amdgcn_rcpf(1.f + __expf(-v));
}

// ---------------------------------------------------------------------------
// Kernel 1: encoder. 2 batch rows per block, 512 threads, fp32 VALU.
// (unchanged)
// ---------------------------------------------------------------------------
__global__ __launch_bounds__(512) void enc_kernel(
    const void* __restrict__ x_seq, const void* __restrict__ tvec,
    const void* __restrict__ epsp,
    const void* __restrict__ ew1, const void* __restrict__ eb1,
    const void* __restrict__ ew2, const void* __restrict__ eb2,
    const void* __restrict__ ew3, const void* __restrict__ eb3,
    const void* __restrict__ muw, const void* __restrict__ mub,
    const void* __restrict__ lvw, const void* __restrict__ lvb,
    float* __restrict__ out, float* __restrict__ z0f)
{
    __shared__ __align__(16) float xs[2][512];
    __shared__ __align__(16) float h1[2][512];
    __shared__ __align__(16) float h2[2][256];
    __shared__ __align__(16) float h3[2][128];
    __shared__ float muv[2][64], lvv[2][64];
    const bool m = detect_f32(tvec);
    const int t = threadIdx.x;
    const int b0 = blockIdx.x * 2;

    xs[0][t] = loadf(x_seq, (long)(b0 + 0) * 102400 + t, m);
    xs[1][t] = loadf(x_seq, (long)(b0 + 1) * 102400 + t, m);
    __syncthreads();

    // L1: 512 -> 512, one neuron per thread
    {
        float a0 = 0.f, a1 = 0.f;
        const float4* x0v = (const float4*)xs[0];
        const float4* x1v = (const float4*)xs[1];
        #pragma unroll 4
        for (int j4 = 0; j4 < 128; ++j4) {
            float4 xa = x0v[j4], xb = x1v[j4];
            float w0 = loadf(ew1, (4 * j4 + 0) * 512 + t, m);
            float w1v = loadf(ew1, (4 * j4 + 1) * 512 + t, m);
            float w2v = loadf(ew1, (4 * j4 + 2) * 512 + t, m);
            float w3v = loadf(ew1, (4 * j4 + 3) * 512 + t, m);
            a0 += xa.x * w0 + xa.y * w1v + xa.z * w2v + xa.w * w3v;
            a1 += xb.x * w0 + xb.y * w1v + xb.z * w2v + xb.w * w3v;
        }
        float bb = loadf(eb1, t, m);
        h1[0][t] = fmaxf(a0 + bb, 0.f);
        h1[1][t] = fmaxf(a1 + bb, 0.f);
    }
    __syncthreads();

    // L2: 512 -> 256, 2 threads per neuron
    {
        const int i = t >> 1, s = t & 1;
        float a0 = 0.f, a1 = 0.f;
        const float4* p0 = (const float4*)&h1[0][s * 256];
        const float4* p1 = (const float4*)&h1[1][s * 256];
        #pragma unroll 4
        for (int j4 = 0; j4 < 64; ++j4) {
            float4 xa = p0[j4], xb = p1[j4];
            int j = s * 256 + 4 * j4;
            float w0 = loadf(ew2, (j + 0) * 256 + i, m);
            float w1v = loadf(ew2, (j + 1) * 256 + i, m);
            float w2v = loadf(ew2, (j + 2) * 256 + i, m);
            float w3v = loadf(ew2, (j + 3) * 256 + i, m);
            a0 += xa.x * w0 + xa.y * w1v + xa.z * w2v + xa.w * w3v;
            a1 += xb.x * w0 + xb.y * w1v + xb.z * w2v + xb.w * w3v;
        }
        a0 += __shfl_xor(a0, 1);
        a1 += __shfl_xor(a1, 1);
        if (s == 0) {
            float bb = loadf(eb2, i, m);
            h2[0][i] = fmaxf(a0 + bb, 0.f);
            h2[1][i] = fmaxf(a1 + bb, 0.f);
        }
    }
    __syncthreads();

    // L3: 256 -> 128, 4 threads per neuron
    {
        const int i = t >> 2, s = t & 3;
        float a0 = 0.f, a1 = 0.f;
        const float4* p0 = (const float4*)&h2[0][s * 64];
        const float4* p1 = (const float4*)&h2[1][s * 64];
        #pragma unroll 4
        for (int j4 = 0; j4 < 16; ++j4) {
            float4 xa = p0[j4], xb = p1[j4];
            int j = s * 64 + 4 * j4;
            float w0 = loadf(ew3, (j + 0) * 128 + i, m);
            float w1v = loadf(ew3, (j + 1) * 128 + i, m);
            float w2v = loadf(ew3, (j + 2) * 128 + i, m);
            float w3v = loadf(ew3, (j + 3) * 128 + i, m);
            a0 += xa.x * w0 + xa.y * w1v + xa.z * w2v + xa.w * w3v;
            a1 += xb.x * w0 + xb.y * w1v + xb.z * w2v + xb.w * w3v;
        }
        a0 += __shfl_xor(a0, 1); a0 += __shfl_xor(a0, 2);
        a1 += __shfl_xor(a1, 1); a1 += __shfl_xor(a1, 2);
        if (s == 0) {
            float bb = loadf(eb3, i, m);
            h3[0][i] = fmaxf(a0 + bb, 0.f);
            h3[1][i] = fmaxf(a1 + bb, 0.f);
        }
    }
    __syncthreads();

    // mu / logvar heads: 128 -> 64 each
    {
        const int o = t >> 2, s = t & 3;
        const void* wp; const void* bp; int oc;
        if (o < 64) { wp = muw; bp = mub; oc = o; }
        else        { wp = lvw; bp = lvb; oc = o - 64; }
        float a0 = 0.f, a1 = 0.f;
        const float4* p0 = (const float4*)&h3[0][s * 32];
        const float4* p1 = (const float4*)&h3[1][s * 32];
        #pragma unroll
        for (int j4 = 0; j4 < 8; ++j4) {
            float4 xa = p0[j4], xb = p1[j4];
            int j = s * 32 + 4 * j4;
            float w0 = loadf(wp, (j + 0) * 64 + oc, m);
            float w1v = loadf(wp, (j + 1) * 64 + oc, m);
            float w2v = loadf(wp, (j + 2) * 64 + oc, m);
            float w3v = loadf(wp, (j + 3) * 64 + oc, m);
            a0 += xa.x * w0 + xa.y * w1v + xa.z * w2v + xa.w * w3v;
            a1 += xb.x * w0 + xb.y * w1v + xb.z * w2v + xb.w * w3v;
        }
        a0 += __shfl_xor(a0, 1); a0 += __shfl_xor(a0, 2);
        a1 += __shfl_xor(a1, 1); a1 += __shfl_xor(a1, 2);
        if (s == 0) {
            float bb = loadf(bp, oc, m);
            if (o < 64) { muv[0][oc] = a0 + bb; muv[1][oc] = a1 + bb; }
            else        { lvv[0][oc] = a0 + bb; lvv[1][oc] = a1 + bb; }
        }
    }
    __syncthreads();

    if (t < 128) {
        int r = t >> 6, d = t & 63;
        float mm = muv[r][d], l = lvv[r][d];
        float z = mm + expf(0.5f * l) * loadf(epsp, (b0 + r) * 64 + d, m);
        z0f[(b0 + r) * 64 + d] = z;
        out[MU_OFF + (b0 + r) * 64 + d] = mm;
        out[LV_OFF + (b0 + r) * 64 + d] = l;
    }
}

// ---------------------------------------------------------------------------
// Kernel 2: ODE RK4 — WAVE-LOCAL MFMA rewrite. ZERO barriers in the loop.
//
//   One wave (64 threads) per block owns 16 batch rows for all 199 steps.
//   Grid = 16 blocks (16 CUs, latency-bound by design).
//
//   The weight A-frag rows of every layer are PERMUTED:
//     n = perm(t, rho) = 32*(t>>1) + 8*(rho>>2) + 4*(t&1) + (rho&3)
//   With this permutation the MFMA C-output of layer k (lane (lh,lm) holds
//   n = 32*(t>>1)+8*lh+4*(t&1)+r, batch=lm) is EXACTLY the B-frag layout
//   of layer k+1 (lane needs act[k=32*kt+8*lh+j], j=0..7, from tiles
//   2kt/2kt+1, j=4*(t&1)+r). So L1->L2->L3->LN->RK->L1 needs NO cross-lane
//   movement except 2x2 shfl_xor in the LN reduction.
//
//   State zbr/kar/zeval stays fp32 in regs; z enters MFMA as hi+lo bf16
//   split (~16 mantissa bits on the recurrent path). h1/h2 plain bf16.
//   Biases/LN params in conflict-free per-lane LDS tables [tile][lane]
//   (read-only; single wave per block -> no barriers needed).
// ---------------------------------------------------------------------------
__device__ __forceinline__ int permn(int t, int rho) {
    return 32 * (t >> 1) + 8 * (rho >> 2) + 4 * (t & 1) + (rho & 3);
}

__global__ __launch_bounds__(64, 1) void ode_kernel(
    const void* __restrict__ tvec,
    const void* __restrict__ w1, const void* __restrict__ b1,
    const void* __restrict__ w2, const void* __restrict__ b2,
    const void* __restrict__ w3, const void* __restrict__ b3,
    const void* __restrict__ lng, const void* __restrict__ lnb,
    const float* __restrict__ z0f,
    float* __restrict__ zt_out, float* __restrict__ zd_out)
{
    __shared__ float dts[200];
    __shared__ __align__(16) float4 B1t[8][64];
    __shared__ __align__(16) float4 B2t[8][64];
    __shared__ __align__(16) float4 B3t[4][64];
    __shared__ __align__(16) float4 Gt[4][64];
    __shared__ __align__(16) float4 BNt[4][64];

    const bool m = detect_f32(tvec);
    const int l = threadIdx.x;           // 0..63, single wave
    const int lm = l & 15;               // batch column
    const int lh = l >> 4;               // k-group / C row-group
    const int r0 = blockIdx.x * 16;      // batch base

    union FR { bf8v v; unsigned int u[4]; };

    // ---- weight A-frags (permuted rows). frag[t][kt] short j: W[k][perm(t,lm)]
    bf8v a1f[8][2], a2f[8][4], a3f[4][4];
    #pragma unroll
    for (int t = 0; t < 8; ++t) {
        const int n1 = permn(t, lm);
        #pragma unroll
        for (int kt = 0; kt < 2; ++kt) {
            FR f;
            #pragma unroll
            for (int p = 0; p < 4; ++p) {
                int k = kt * 32 + lh * 8 + 2 * p;
                f.u[p] = cvtpk2(loadf(w1, (long)k * 128 + n1, m),
                                loadf(w1, (long)(k + 1) * 128 + n1, m));
            }
            a1f[t][kt] = f.v;
        }
        #pragma unroll
        for (int kt = 0; kt < 4; ++kt) {
            FR f;
            #pragma unroll
            for (int p = 0; p < 4; ++p) {
                int k = kt * 32 + lh * 8 + 2 * p;
                f.u[p] = cvtpk2(loadf(w2, (long)k * 128 + n1, m),
                                loadf(w2, (long)(k + 1) * 128 + n1, m));
            }
            a2f[t][kt] = f.v;
        }
    }
    #pragma unroll
    for (int t = 0; t < 4; ++t) {
        const int n3 = permn(t, lm);
        #pragma unroll
        for (int kt = 0; kt < 4; ++kt) {
            FR f;
            #pragma unroll
            for (int p = 0; p < 4; ++p) {
                int k = kt * 32 + lh * 8 + 2 * p;
                f.u[p] = cvtpk2(loadf(w3, (long)k * 64 + n3, m),
                                loadf(w3, (long)(k + 1) * 64 + n3, m));
            }
            a3f[t][kt] = f.v;
        }
    }

    // ---- bias / LN tables into LDS (per-lane float4, conflict-free)
    #pragma unroll
    for (int t = 0; t < 8; ++t) {
        const int nb = 32 * (t >> 1) + 8 * lh + 4 * (t & 1);   // = perm(t,4*lh)
        float4 v1, v2;
        v1.x = loadf(b1, nb + 0, m); v1.y = loadf(b1, nb + 1, m);
        v1.z = loadf(b1, nb + 2, m); v1.w = loadf(b1, nb + 3, m);
        v2.x = loadf(b2, nb + 0, m); v2.y = loadf(b2, nb + 1, m);
        v2.z = loadf(b2, nb + 2, m); v2.w = loadf(b2, nb + 3, m);
        B1t[t][l] = v1; B2t[t][l] = v2;
    }
    #pragma unroll
    for (int t = 0; t < 4; ++t) {
        const int nb = 32 * (t >> 1) + 8 * lh + 4 * (t & 1);
        float4 v1, v2, v3;
        v1.x = loadf(b3, nb + 0, m); v1.y = loadf(b3, nb + 1, m);
        v1.z = loadf(b3, nb + 2, m); v1.w = loadf(b3, nb + 3, m);
        v2.x = loadf(lng, nb + 0, m); v2.y = loadf(lng, nb + 1, m);
        v2.z = loadf(lng, nb + 2, m); v2.w = loadf(lng, nb + 3, m);
        v3.x = loadf(lnb, nb + 0, m); v3.y = loadf(lnb, nb + 1, m);
        v3.z = loadf(lnb, nb + 2, m); v3.w = loadf(lnb, nb + 3, m);
        B3t[t][l] = v1; Gt[t][l] = v2; BNt[t][l] = v3;
    }
    for (int i = l; i < 199; i += 64)
        dts[i] = loadf(tvec, i + 1, m) - loadf(tvec, i, m);
    __syncthreads();   // single wave: cheap; orders LDS init vs loop reads

    // ---- RK state (fp32 regs). index [4*t3 + r] <-> n = 32*(t3>>1)+8*lh+4*(t3&1)+r
    float zbr[16], kar[16], zeval[16];
    #pragma unroll
    for (int t3 = 0; t3 < 4; ++t3) {
        const int nb = 32 * (t3 >> 1) + 8 * lh + 4 * (t3 & 1);
        float4 zv = *(const float4*)&z0f[(long)(r0 + lm) * 64 + nb];
        zbr[4 * t3 + 0] = zv.x; zbr[4 * t3 + 1] = zv.y;
        zbr[4 * t3 + 2] = zv.z; zbr[4 * t3 + 3] = zv.w;
        *(float4*)&zt_out[(long)(r0 + lm) * 12800 + nb] = zv;   // step 0
    }
    #pragma unroll
    for (int i = 0; i < 16; ++i) { zeval[i] = zbr[i]; kar[i] = 0.f; }

    #pragma unroll 1
    for (int step = 0; step < 199; ++step) {
        const float hstep = dts[step];
        #pragma unroll
        for (int e = 0; e < 4; ++e) {
            // ---- build z B-frags hi+lo from zeval (frag kt short j = zeval[8kt+j])
            FR zh[2], zl[2];
            #pragma unroll
            for (int kt = 0; kt < 2; ++kt) {
                #pragma unroll
                for (int p = 0; p < 4; ++p) {
                    float za = zeval[8 * kt + 2 * p], zb = zeval[8 * kt + 2 * p + 1];
                    unsigned int hp = cvtpk2(za, zb);
                    zh[kt].u[p] = hp;
                    float ha = __uint_as_float(hp << 16);
                    float hb = __uint_as_float(hp & 0xffff0000u);
                    zl[kt].u[p] = cvtpk2(za - ha, zb - hb);
                }
            }
            // ---- L1: h1 = silu(W1^T z + b1); outputs packed straight into B-frags
            FR hf[4];
            #pragma unroll
            for (int kt = 0; kt < 4; ++kt) {
                float s[8];
                #pragma unroll
                for (int half = 0; half < 2; ++half) {
                    const int t = 2 * kt + half;
                    f32x4 acc = {0.f, 0.f, 0.f, 0.f};
                    acc = __builtin_amdgcn_mfma_f32_16x16x32_bf16(a1f[t][0], zh[0].v, acc, 0, 0, 0);
                    acc = __builtin_amdgcn_mfma_f32_16x16x32_bf16(a1f[t][1], zh[1].v, acc, 0, 0, 0);
                    acc = __builtin_amdgcn_mfma_f32_16x16x32_bf16(a1f[t][0], zl[0].v, acc, 0, 0, 0);
                    acc = __builtin_amdgcn_mfma_f32_16x16x32_bf16(a1f[t][1], zl[1].v, acc, 0, 0, 0);
                    float4 bb = B1t[t][l];
                    s[4 * half + 0] = silu_f(acc.x + bb.x);
                    s[4 * half + 1] = silu_f(acc.y + bb.y);
                    s[4 * half + 2] = silu_f(acc.z + bb.z);
                    s[4 * half + 3] = silu_f(acc.w + bb.w);
                }
                hf[kt].u[0] = cvtpk2(s[0], s[1]); hf[kt].u[1] = cvtpk2(s[2], s[3]);
                hf[kt].u[2] = cvtpk2(s[4], s[5]); hf[kt].u[3] = cvtpk2(s[6], s[7]);
            }
            // ---- L2: h2 = silu(W2^T h1 + b2)
            FR gf[4];
            #pragma unroll
            for (int kt = 0; kt < 4; ++kt) {
                float s[8];
                #pragma unroll
                for (int half = 0; half < 2; ++half) {
                    const int t = 2 * kt + half;
                    f32x4 acc = {0.f, 0.f, 0.f, 0.f};
                    #pragma unroll
                    for (int kk = 0; kk < 4; ++kk)
                        acc = __builtin_amdgcn_mfma_f32_16x16x32_bf16(a2f[t][kk], hf[kk].v, acc, 0, 0, 0);
                    float4 bb = B2t[t][l];
                    s[4 * half + 0] = silu_f(acc.x + bb.x);
                    s[4 * half + 1] = silu_f(acc.y + bb.y);
                    s[4 * half + 2] = silu_f(acc.z + bb.z);
                    s[4 * half + 3] = silu_f(acc.w + bb.w);
                }
                gf[kt].u[0] = cvtpk2(s[0], s[1]); gf[kt].u[1] = cvtpk2(s[2], s[3]);
                gf[kt].u[2] = cvtpk2(s[4], s[5]); gf[kt].u[3] = cvtpk2(s[6], s[7]);
            }
            // ---- L3: dz = W3^T h2 + b3
            float dz[16];
            #pragma unroll
            for (int t3 = 0; t3 < 4; ++t3) {
                f32x4 acc = {0.f, 0.f, 0.f, 0.f};
                #pragma unroll
                for (int kk = 0; kk < 4; ++kk)
                    acc = __builtin_amdgcn_mfma_f32_16x16x32_bf16(a3f[t3][kk], gf[kk].v, acc, 0, 0, 0);
                float4 bb = B3t[t3][l];
                dz[4 * t3 + 0] = acc.x + bb.x;
                dz[4 * t3 + 1] = acc.y + bb.y;
                dz[4 * t3 + 2] = acc.z + bb.z;
                dz[4 * t3 + 3] = acc.w + bb.w;
            }
            // ---- LN over 64 n (lane has 16; xor16+xor32 sum across lh groups)
            float S = 0.f, SS = 0.f;
            #pragma unroll
            for (int i = 0; i < 16; ++i) { S += dz[i]; SS = fmaf(dz[i], dz[i], SS); }
            S  += __shfl_xor(S, 16);  S  += __shfl_xor(S, 32);
            SS += __shfl_xor(SS, 16); SS += __shfl_xor(SS, 32);
            const float mean = S * (1.f / 64.f);
            const float var  = SS * (1.f / 64.f) - mean * mean;
            const float rstd = rsqrtf(var + 1e-5f);
            // ---- RK bookkeeping (fully in-register)
            float zc[16];
            #pragma unroll
            for (int t3 = 0; t3 < 4; ++t3) {
                float4 gg = Gt[t3][l], bb = BNt[t3][l];
                #pragma unroll
                for (int r = 0; r < 4; ++r) {
                    const int i = 4 * t3 + r;
                    float gv = (r == 0) ? gg.x : (r == 1) ? gg.y : (r == 2) ? gg.z : gg.w;
                    float bv = (r == 0) ? bb.x : (r == 1) ? bb.y : (r == 2) ? bb.z : bb.w;
                    float y = (dz[i] - mean) * rstd * gv + bv;
                    if (e == 0)      { kar[i] = y;          zc[i] = zbr[i] + 0.5f * hstep * y; }
                    else if (e == 1) { kar[i] += 2.f * y;   zc[i] = zbr[i] + 0.5f * hstep * y; }
                    else if (e == 2) { kar[i] += 2.f * y;   zc[i] = zbr[i] + hstep * y; }
                    else             { kar[i] += y;         zc[i] = zbr[i] + (hstep * (1.f / 6.f)) * kar[i]; }
                }
            }
            if (e == 3) {
                const float rh = 1.f / hstep;
                #pragma unroll
                for (int t3 = 0; t3 < 4; ++t3) {
                    const int nb = 32 * (t3 >> 1) + 8 * lh + 4 * (t3 & 1);
                    float4 o1, o2;
                    o1.x = zc[4 * t3 + 0]; o1.y = zc[4 * t3 + 1];
                    o1.z = zc[4 * t3 + 2]; o1.w = zc[4 * t3 + 3];
                    o2.x = (zc[4 * t3 + 0] - zbr[4 * t3 + 0]) * rh;
                    o2.y = (zc[4 * t3 + 1] - zbr[4 * t3 + 1]) * rh;
                    o2.z = (zc[4 * t3 + 2] - zbr[4 * t3 + 2]) * rh;
                    o2.w = (zc[4 * t3 + 3] - zbr[4 * t3 + 3]) * rh;
                    *(float4*)&zt_out[(long)(r0 + lm) * 12800 + (step + 1) * 64 + nb] = o1;
                    *(float4*)&zd_out[(long)(r0 + lm) * 12736 + step * 64 + nb] = o2;
                }
                #pragma unroll
                for (int i = 0; i < 16; ++i) zbr[i] = zc[i];
            }
            #pragma unroll
            for (int i = 0; i < 16; ++i) zeval[i] = zc[i];
        }
    }
}

// ---------------------------------------------------------------------------
// Kernel 2.5: weight transpose + bf16 pack for the decoder GEMMs (unchanged).
// ---------------------------------------------------------------------------
__global__ __launch_bounds__(256) void wt_kernel(
    const void* __restrict__ w1, const void* __restrict__ w2,
    const void* __restrict__ w3, const void* __restrict__ tvec,
    u16* __restrict__ wt1, u16* __restrict__ wt2, u16* __restrict__ wt3)
{
    __shared__ u16 tile[64][65];
    const bool m = detect_f32(tvec);
    const int b = blockIdx.x;
    const void* src; u16* dst; int K, kt, nt0;
    if (b < 8)       { src = w1; dst = wt1; K = 64;  kt = 0;          nt0 = b; }
    else if (b < 72) { src = w2; dst = wt2; K = 512; kt = (b-8) >> 3; nt0 = (b-8) & 7; }
    else             { src = w3; dst = wt3; K = 512; kt = (b-72) >> 3; nt0 = (b-72) & 7; }
    const int k0 = kt * 64, n0 = nt0 * 64;
    const int t = threadIdx.x;
    #pragma unroll
    for (int i = 0; i < 16; ++i) {
        int idx = t + 256 * i;                // 4096 elements per 64x64 tile
        int r = idx >> 6, c = idx & 63;       // r = k offset, c = n offset
        tile[r][c] = f2bf(loadf(src, (long)(k0 + r) * 512 + n0 + c, m));
    }
    __syncthreads();
    #pragma unroll
    for (int i = 0; i < 16; ++i) {
        int idx = t + 256 * i;
        int c = idx >> 6, r = idx & 63;       // c = n offset, r = k offset
        int pk = ((r >> 3) & 3) * 16 + ((r >> 5) & 1) * 8 + (r & 7);
        dst[(long)(n0 + c) * K + k0 + pk] = tile[r][c];
    }
}

// ---------------------------------------------------------------------------
// Kernel 3: decoder — bf16 MFMA GEMM chain (unchanged, verified round 1).
// ---------------------------------------------------------------------------
template<int K, int INROWB, bool RELU, bool TOLDS>
__device__ __forceinline__ void dec_layer(
    const u16* __restrict__ WT, const float* __restrict__ bl,
    const u16* Xin, u16* Xout, float* __restrict__ gout,
    long r0, int w, int lm, int lh)
{
    f32x4 acc[8][4];
    #pragma unroll
    for (int a = 0; a < 8; ++a)
        #pragma unroll
        for (int b = 0; b < 4; ++b) { f32x4 z4 = {0.f, 0.f, 0.f, 0.f}; acc[a][b] = z4; }

    #pragma unroll 1
    for (int kk2 = 0; kk2 < K / 64; ++kk2) {
        #pragma unroll
        for (int half = 0; half < 2; ++half) {
            const int kb = kk2 * 64 + half * 32 + lh * 8;   // logical k base
            bf8v bfr[4];
            #pragma unroll
            for (int mt = 0; mt < 4; ++mt) {
                int mr = mt * 16 + lm;
                int byte = mr * INROWB + kb * 2;
                bfr[mt] = *(const bf8v*)((const char*)Xin + (byte ^ ((mr & 7) << 4)));
            }
            bf8v afr[8];
            #pragma unroll
            for (int nt = 0; nt < 8; ++nt) {
                int n = w * 128 + nt * 16 + lm;
                afr[nt] = *(const bf8v*)&WT[(long)n * K + kk2 * 64 + lh * 16 + half * 8];
            }
            #pragma unroll
            for (int nt = 0; nt < 8; ++nt)
                #pragma unroll
                for (int mt = 0; mt < 4; ++mt)
                    acc[nt][mt] = __builtin_amdgcn_mfma_f32_16x16x32_bf16(
                        afr[nt], bfr[mt], acc[nt][mt], 0, 0, 0);
        }
    }
    __syncthreads();   // all Xin reads complete (required before in-place overwrite)

    // epilogue: bias (+relu), then bf16->LDS (8B packed) or fp32->global
    #pragma unroll
    for (int nt = 0; nt < 8; ++nt) {
        const int n0 = w * 128 + nt * 16 + lh * 4;     // D row = lh*4 + reg (m89)
        f32x4 bv = *(const f32x4*)&bl[n0];
        #pragma unroll
        for (int mt = 0; mt < 4; ++mt) {
            f32x4 v = acc[nt][mt];
            v.x += bv.x; v.y += bv.y; v.z += bv.z; v.w += bv.w;
            if (RELU) {
                v.x = fmaxf(v.x, 0.f); v.y = fmaxf(v.y, 0.f);
                v.z = fmaxf(v.z, 0.f); v.w = fmaxf(v.w, 0.f);
            }
            const int mr = mt * 16 + lm;               // D col = lane&15 (m89)
            if (TOLDS) {
                bf4v h;
                h.x = (short)f2bf(v.x); h.y = (short)f2bf(v.y);
                h.z = (short)f2bf(v.z); h.w = (short)f2bf(v.w);
                int byte = mr * 1024 + n0 * 2;
                *(bf4v*)((char*)Xout + (byte ^ ((mr & 7) << 4))) = h;
            } else {
                *(f32x4*)&gout[(r0 + mr) * 512 + n0] = v;
            }
        }
    }
    __syncthreads();   // Xout visible to all waves
}

__global__ __launch_bounds__(256, 2) void dec_kernel(
    const float* __restrict__ zt, const void* __restrict__ tvec,
    const u16* __restrict__ wt1, const u16* __restrict__ wt2,
    const u16* __restrict__ wt3,
    const void* __restrict__ b1, const void* __restrict__ b2,
    const void* __restrict__ b3,
    float* __restrict__ xhat)
{
    __shared__ __align__(16) u16 X0[64 * 64];     // z tile, bf16, row=128B, swizzled
    __shared__ __align__(16) u16 X1[64 * 512];    // activation, row=1024B, swizzled
    __shared__ __align__(16) float bl1[512], bl2[512], bl3[512];

    const bool m = detect_f32(tvec);
    const int t = threadIdx.x;
    const int l = t & 63, w = t >> 6;
    const int lm = l & 15, lh = l >> 4;
    const long r0 = (long)blockIdx.x * 8 * 8;

    // stage biases to LDS (fp32)
    bl1[t] = loadf(b1, t, m); bl1[t + 256] = loadf(b1, t + 256, m);
    bl2[t] = loadf(b2, t, m); bl2[t + 256] = loadf(b2, t + 256, m);
    bl3[t] = loadf(b3, t, m); bl3[t + 256] = loadf(b3, t + 256, m);

    // stage z rows (fp32 global) -> X0 bf16, swizzled
    {
        const int mrow = t >> 2;
        const int c0 = (t & 3) * 16;
        const float* zr = zt + (r0 + mrow) * 64 + c0;
        #pragma unroll
        for (int j = 0; j < 4; ++j) {
            float4 v = *(const float4*)(zr + 4 * j);
            bf4v h;
            h.x = (short)f2bf(v.x); h.y = (short)f2bf(v.y);
            h.z = (short)f2bf(v.z); h.w = (short)f2bf(v.w);
            int byte = mrow * 128 + (c0 + 4 * j) * 2;
            *(bf4v*)((char*)X0 + (byte ^ ((mrow & 7) << 4))) = h;
        }
    }
    __syncthreads();

    dec_layer< 64,  128, true,  true >(wt1, bl1, X0, X1, nullptr, r0, w, lm, lh);
    dec_layer<512, 1024, true,  true >(wt2, bl2, X1, X1, nullptr, r0, w, lm, lh);
    dec_layer<512, 1024, false, false>(wt3, bl3, X1, nullptr, xhat, r0, w, lm, lh);
}

// ---------------------------------------------------------------------------
extern "C" void kernel_launch(void* const* d_in, const int* in_sizes, int n_in,
                              void* d_out, int out_size, void* d_ws, size_t ws_size,
                              hipStream_t stream)
{
    float* out = (float*)d_out;
    float* z0f = (float*)d_ws;                                   // 64 KB
    u16* wt1 = (u16*)((char*)d_ws + 65536);                      // 512x64  bf16 = 64 KB
    u16* wt2 = (u16*)((char*)d_ws + 65536 + 65536);              // 512x512 bf16 = 512 KB
    u16* wt3 = (u16*)((char*)d_ws + 65536 + 65536 + 524288);     // 512x512 bf16 = 512 KB

    // decoder weight transpose/pack (independent of enc/ode)
    wt_kernel<<<136, 256, 0, stream>>>(
        d_in[21], d_in[23], d_in[25], d_in[1], wt1, wt2, wt3);

    enc_kernel<<<128, 512, 0, stream>>>(
        d_in[0], d_in[1], d_in[2], d_in[3], d_in[4], d_in[5], d_in[6],
        d_in[7], d_in[8], d_in[9], d_in[10], d_in[11], d_in[12],
        out, z0f);

    ode_kernel<<<16, 64, 0, stream>>>(
        d_in[1], d_in[13], d_in[14], d_in[15], d_in[16],
        d_in[17], d_in[18], d_in[19], d_in[20], z0f,
        out + ZT_OFF, out + ZD_OFF);

    dec_kernel<<<800, 256, 0, stream>>>(
        out + ZT_OFF, d_in[1], wt1, wt2, wt3,
        d_in[22], d_in[24], d_in[26], out);
}

// Round 5
// 2016.941 us; speedup vs baseline: 1.1383x; 1.1383x over previous
//
#include <hip/hip_runtime.h>

typedef unsigned short u16;

// ---- problem constants ----
#define BB 256
#define LL 200
#define NN 512
#define DD 64
#define HH 128

// d_out element offsets (fp32 elements)
#define MU_OFF   26214400
#define LV_OFF   26230784
#define ZT_OFF   26247168
#define ZD_OFF   29523968

typedef __attribute__((ext_vector_type(8))) short bf8v;   // 8 bf16 (4 VGPRs) MFMA frag
typedef __attribute__((ext_vector_type(4))) short bf4v;   // 4 bf16 (8B)
typedef __attribute__((ext_vector_type(4))) float f32x4;  // MFMA accum

__device__ __forceinline__ float bf2f(u16 u) {
    union { unsigned int i; float f; } v; v.i = ((unsigned int)u) << 16; return v.f;
}
__device__ __forceinline__ u16 f2bf(float f) {
    union { float f; unsigned int u; } v; v.f = f;
    unsigned int r = v.u + 0x7FFFu + ((v.u >> 16) & 1u);   // RNE
    return (u16)(r >> 16);
}
// Runtime input-dtype probe: tvec[199] as bf16 reads ~1.99 if inputs are
// bf16; if fp32, u16[199] is the high half of float tvec[99] (~0.988).
__device__ __forceinline__ bool detect_f32(const void* tvec) {
    float v = bf2f(((const u16*)tvec)[199]);
    return !(v > 1.5f && v < 2.5f);
}
__device__ __forceinline__ float loadf(const void* p, long idx, bool f32m) {
    return f32m ? ((const float*)p)[idx] : bf2f(((const u16*)p)[idx]);
}

// ---------------------------------------------------------------------------
// Kernel 1: encoder. 2 batch rows per block, 512 threads, fp32 VALU.
// (unchanged, verified)
// ---------------------------------------------------------------------------
__global__ __launch_bounds__(512) void enc_kernel(
    const void* __restrict__ x_seq, const void* __restrict__ tvec,
    const void* __restrict__ epsp,
    const void* __restrict__ ew1, const void* __restrict__ eb1,
    const void* __restrict__ ew2, const void* __restrict__ eb2,
    const void* __restrict__ ew3, const void* __restrict__ eb3,
    const void* __restrict__ muw, const void* __restrict__ mub,
    const void* __restrict__ lvw, const void* __restrict__ lvb,
    float* __restrict__ out, float* __restrict__ z0f)
{
    __shared__ __align__(16) float xs[2][512];
    __shared__ __align__(16) float h1[2][512];
    __shared__ __align__(16) float h2[2][256];
    __shared__ __align__(16) float h3[2][128];
    __shared__ float muv[2][64], lvv[2][64];
    const bool m = detect_f32(tvec);
    const int t = threadIdx.x;
    const int b0 = blockIdx.x * 2;

    xs[0][t] = loadf(x_seq, (long)(b0 + 0) * 102400 + t, m);
    xs[1][t] = loadf(x_seq, (long)(b0 + 1) * 102400 + t, m);
    __syncthreads();

    // L1: 512 -> 512, one neuron per thread
    {
        float a0 = 0.f, a1 = 0.f;
        const float4* x0v = (const float4*)xs[0];
        const float4* x1v = (const float4*)xs[1];
        #pragma unroll 4
        for (int j4 = 0; j4 < 128; ++j4) {
            float4 xa = x0v[j4], xb = x1v[j4];
            float w0 = loadf(ew1, (4 * j4 + 0) * 512 + t, m);
            float w1v = loadf(ew1, (4 * j4 + 1) * 512 + t, m);
            float w2v = loadf(ew1, (4 * j4 + 2) * 512 + t, m);
            float w3v = loadf(ew1, (4 * j4 + 3) * 512 + t, m);
            a0 += xa.x * w0 + xa.y * w1v + xa.z * w2v + xa.w * w3v;
            a1 += xb.x * w0 + xb.y * w1v + xb.z * w2v + xb.w * w3v;
        }
        float bb = loadf(eb1, t, m);
        h1[0][t] = fmaxf(a0 + bb, 0.f);
        h1[1][t] = fmaxf(a1 + bb, 0.f);
    }
    __syncthreads();

    // L2: 512 -> 256, 2 threads per neuron
    {
        const int i = t >> 1, s = t & 1;
        float a0 = 0.f, a1 = 0.f;
        const float4* p0 = (const float4*)&h1[0][s * 256];
        const float4* p1 = (const float4*)&h1[1][s * 256];
        #pragma unroll 4
        for (int j4 = 0; j4 < 64; ++j4) {
            float4 xa = p0[j4], xb = p1[j4];
            int j = s * 256 + 4 * j4;
            float w0 = loadf(ew2, (j + 0) * 256 + i, m);
            float w1v = loadf(ew2, (j + 1) * 256 + i, m);
            float w2v = loadf(ew2, (j + 2) * 256 + i, m);
            float w3v = loadf(ew2, (j + 3) * 256 + i, m);
            a0 += xa.x * w0 + xa.y * w1v + xa.z * w2v + xa.w * w3v;
            a1 += xb.x * w0 + xb.y * w1v + xb.z * w2v + xb.w * w3v;
        }
        a0 += __shfl_xor(a0, 1);
        a1 += __shfl_xor(a1, 1);
        if (s == 0) {
            float bb = loadf(eb2, i, m);
            h2[0][i] = fmaxf(a0 + bb, 0.f);
            h2[1][i] = fmaxf(a1 + bb, 0.f);
        }
    }
    __syncthreads();

    // L3: 256 -> 128, 4 threads per neuron
    {
        const int i = t >> 2, s = t & 3;
        float a0 = 0.f, a1 = 0.f;
        const float4* p0 = (const float4*)&h2[0][s * 64];
        const float4* p1 = (const float4*)&h2[1][s * 64];
        #pragma unroll 4
        for (int j4 = 0; j4 < 16; ++j4) {
            float4 xa = p0[j4], xb = p1[j4];
            int j = s * 64 + 4 * j4;
            float w0 = loadf(ew3, (j + 0) * 128 + i, m);
            float w1v = loadf(ew3, (j + 1) * 128 + i, m);
            float w2v = loadf(ew3, (j + 2) * 128 + i, m);
            float w3v = loadf(ew3, (j + 3) * 128 + i, m);
            a0 += xa.x * w0 + xa.y * w1v + xa.z * w2v + xa.w * w3v;
            a1 += xb.x * w0 + xb.y * w1v + xb.z * w2v + xb.w * w3v;
        }
        a0 += __shfl_xor(a0, 1); a0 += __shfl_xor(a0, 2);
        a1 += __shfl_xor(a1, 1); a1 += __shfl_xor(a1, 2);
        if (s == 0) {
            float bb = loadf(eb3, i, m);
            h3[0][i] = fmaxf(a0 + bb, 0.f);
            h3[1][i] = fmaxf(a1 + bb, 0.f);
        }
    }
    __syncthreads();

    // mu / logvar heads: 128 -> 64 each
    {
        const int o = t >> 2, s = t & 3;
        const void* wp; const void* bp; int oc;
        if (o < 64) { wp = muw; bp = mub; oc = o; }
        else        { wp = lvw; bp = lvb; oc = o - 64; }
        float a0 = 0.f, a1 = 0.f;
        const float4* p0 = (const float4*)&h3[0][s * 32];
        const float4* p1 = (const float4*)&h3[1][s * 32];
        #pragma unroll
        for (int j4 = 0; j4 < 8; ++j4) {
            float4 xa = p0[j4], xb = p1[j4];
            int j = s * 32 + 4 * j4;
            float w0 = loadf(wp, (j + 0) * 64 + oc, m);
            float w1v = loadf(wp, (j + 1) * 64 + oc, m);
            float w2v = loadf(wp, (j + 2) * 64 + oc, m);
            float w3v = loadf(wp, (j + 3) * 64 + oc, m);
            a0 += xa.x * w0 + xa.y * w1v + xa.z * w2v + xa.w * w3v;
            a1 += xb.x * w0 + xb.y * w1v + xb.z * w2v + xb.w * w3v;
        }
        a0 += __shfl_xor(a0, 1); a0 += __shfl_xor(a0, 2);
        a1 += __shfl_xor(a1, 1); a1 += __shfl_xor(a1, 2);
        if (s == 0) {
            float bb = loadf(bp, oc, m);
            if (o < 64) { muv[0][oc] = a0 + bb; muv[1][oc] = a1 + bb; }
            else        { lvv[0][oc] = a0 + bb; lvv[1][oc] = a1 + bb; }
        }
    }
    __syncthreads();

    if (t < 128) {
        int r = t >> 6, d = t & 63;
        float mm = muv[r][d], l = lvv[r][d];
        float z = mm + expf(0.5f * l) * loadf(epsp, (b0 + r) * 64 + d, m);
        z0f[(b0 + r) * 64 + d] = z;
        out[MU_OFF + (b0 + r) * 64 + d] = mm;
        out[LV_OFF + (b0 + r) * 64 + d] = l;
    }
}

// ---------------------------------------------------------------------------
// Kernel 2: ODE RK4 v3 — 256 threads (4 waves), 1 batch row per block,
// fp32 VALU (v0's verified numerics), 3 barrier segments per RK eval:
//   seg1: L1 (2 thr/neuron, k-half each, 32 FMA, 1 shfl)           -> barrier
//   seg2: L2 (2 thr/neuron, 64 FMA, 1 shfl)                        -> barrier
//   seg3: L3+LN+RK fused on wave 0: lane t<64 holds the FULL W3
//         column (128 f32 VGPRs — occupancy is moot at 1 block/CU),
//         computes dz[t] via 128 FMA from broadcast h2f reads, LN via
//         12-shfl butterfly, RK update, writes zc + outputs         -> barrier
// All in-loop LDS reads are broadcast (same address across lanes) -> no
// bank conflicts. Serial chain ~1750 cy/eval vs v0's ~3800.
// ---------------------------------------------------------------------------
__global__ __launch_bounds__(256, 1) void ode_kernel(
    const void* __restrict__ tvec,
    const void* __restrict__ w1, const void* __restrict__ b1,
    const void* __restrict__ w2, const void* __restrict__ b2,
    const void* __restrict__ w3, const void* __restrict__ b3,
    const void* __restrict__ lng, const void* __restrict__ lnb,
    const float* __restrict__ z0f,
    float* __restrict__ zt_out, float* __restrict__ zd_out)
{
    __shared__ __align__(16) float zc[64];
    __shared__ __align__(16) float h1f[128];
    __shared__ __align__(16) float h2f[128];
    __shared__ float dts[200];

    const bool m = detect_f32(tvec);
    const int t = threadIdx.x;
    const int b = blockIdx.x;
    const int i1 = t >> 1, s1 = t & 1;     // neuron, k-half
    const int t6 = t & 63;

    // ---- weights to registers (all compile-time-indexed; no scratch)
    float w1r[32];                          // L1: k = 32*s1 + j, n = i1
    #pragma unroll
    for (int j = 0; j < 32; ++j)
        w1r[j] = loadf(w1, (long)(32 * s1 + j) * 128 + i1, m);
    float w2r[64];                          // L2: k = 64*s1 + j, n = i1
    #pragma unroll
    for (int j = 0; j < 64; ++j)
        w2r[j] = loadf(w2, (long)(64 * s1 + j) * 128 + i1, m);
    float w3r[128];                         // L3: full column t6 (used by t<64)
    #pragma unroll
    for (int j = 0; j < 128; ++j)
        w3r[j] = loadf(w3, (long)j * 64 + t6, m);

    const float bias1 = loadf(b1, i1, m);
    const float bias2 = loadf(b2, i1, m);
    const float bias3 = loadf(b3, t6, m);
    const float g_ln  = loadf(lng, t6, m);
    const float b_ln  = loadf(lnb, t6, m);

    float zbr = 0.f, kar = 0.f;
    if (t < 64) {
        zbr = z0f[b * 64 + t];
        zc[t] = zbr;
        zt_out[b * 12800 + t] = zbr;
    }
    if (t < 199) dts[t] = loadf(tvec, t + 1, m) - loadf(tvec, t, m);
    __syncthreads();

    #pragma unroll 1
    for (int step = 0; step < 199; ++step) {
        const float h = dts[step];
        #pragma unroll
        for (int e = 0; e < 4; ++e) {
            // ---- seg1: L1 = silu(z @ W1 + b1), 2 thr/neuron (k-halves)
            {
                float a0 = 0.f, a1 = 0.f, a2 = 0.f, a3 = 0.f;
                const float4* zv4 = (const float4*)&zc[32 * s1];
                #pragma unroll
                for (int q = 0; q < 2; ++q) {
                    float4 v0 = zv4[4 * q + 0], v1 = zv4[4 * q + 1];
                    float4 v2 = zv4[4 * q + 2], v3 = zv4[4 * q + 3];
                    a0 += v0.x * w1r[16 * q + 0] + v0.y * w1r[16 * q + 1]
                        + v0.z * w1r[16 * q + 2] + v0.w * w1r[16 * q + 3];
                    a1 += v1.x * w1r[16 * q + 4] + v1.y * w1r[16 * q + 5]
                        + v1.z * w1r[16 * q + 6] + v1.w * w1r[16 * q + 7];
                    a2 += v2.x * w1r[16 * q + 8] + v2.y * w1r[16 * q + 9]
                        + v2.z * w1r[16 * q + 10] + v2.w * w1r[16 * q + 11];
                    a3 += v3.x * w1r[16 * q + 12] + v3.y * w1r[16 * q + 13]
                        + v3.z * w1r[16 * q + 14] + v3.w * w1r[16 * q + 15];
                }
                float a = (a0 + a1) + (a2 + a3);
                a += __shfl_xor(a, 1);
                if (s1 == 0) { float v = a + bias1; h1f[i1] = v / (1.f + expf(-v)); }
            }
            __syncthreads();

            // ---- seg2: L2 = silu(h1 @ W2 + b2), 2 thr/neuron
            {
                float a0 = 0.f, a1 = 0.f, a2 = 0.f, a3 = 0.f;
                const float4* hv4 = (const float4*)&h1f[64 * s1];
                #pragma unroll
                for (int q = 0; q < 4; ++q) {
                    float4 v0 = hv4[4 * q + 0], v1 = hv4[4 * q + 1];
                    float4 v2 = hv4[4 * q + 2], v3 = hv4[4 * q + 3];
                    a0 += v0.x * w2r[16 * q + 0] + v0.y * w2r[16 * q + 1]
                        + v0.z * w2r[16 * q + 2] + v0.w * w2r[16 * q + 3];
                    a1 += v1.x * w2r[16 * q + 4] + v1.y * w2r[16 * q + 5]
                        + v1.z * w2r[16 * q + 6] + v1.w * w2r[16 * q + 7];
                    a2 += v2.x * w2r[16 * q + 8] + v2.y * w2r[16 * q + 9]
                        + v2.z * w2r[16 * q + 10] + v2.w * w2r[16 * q + 11];
                    a3 += v3.x * w2r[16 * q + 12] + v3.y * w2r[16 * q + 13]
                        + v3.z * w2r[16 * q + 14] + v3.w * w2r[16 * q + 15];
                }
                float a = (a0 + a1) + (a2 + a3);
                a += __shfl_xor(a, 1);
                if (s1 == 0) { float v = a + bias2; h2f[i1] = v / (1.f + expf(-v)); }
            }
            __syncthreads();

            // ---- seg3: L3 + LN + RK fused, wave 0 only (t<64)
            if (t < 64) {
                float a0 = 0.f, a1 = 0.f, a2 = 0.f, a3 = 0.f;
                const float4* hv4 = (const float4*)h2f;
                #pragma unroll
                for (int q = 0; q < 8; ++q) {
                    float4 v0 = hv4[4 * q + 0], v1 = hv4[4 * q + 1];
                    float4 v2 = hv4[4 * q + 2], v3 = hv4[4 * q + 3];
                    a0 += v0.x * w3r[16 * q + 0] + v0.y * w3r[16 * q + 1]
                        + v0.z * w3r[16 * q + 2] + v0.w * w3r[16 * q + 3];
                    a1 += v1.x * w3r[16 * q + 4] + v1.y * w3r[16 * q + 5]
                        + v1.z * w3r[16 * q + 6] + v1.w * w3r[16 * q + 7];
                    a2 += v2.x * w3r[16 * q + 8] + v2.y * w3r[16 * q + 9]
                        + v2.z * w3r[16 * q + 10] + v2.w * w3r[16 * q + 11];
                    a3 += v3.x * w3r[16 * q + 12] + v3.y * w3r[16 * q + 13]
                        + v3.z * w3r[16 * q + 14] + v3.w * w3r[16 * q + 15];
                }
                float v = (a0 + a1) + (a2 + a3) + bias3;
                // LN (two-pass butterfly, mirrors v0's rounding)
                float sm = v;
                #pragma unroll
                for (int mm = 1; mm < 64; mm <<= 1) sm += __shfl_xor(sm, mm);
                float mean = sm * (1.f / 64.f);
                float d = v - mean;
                float sq = d * d;
                #pragma unroll
                for (int mm = 1; mm < 64; mm <<= 1) sq += __shfl_xor(sq, mm);
                float var = sq * (1.f / 64.f);
                float y = d / sqrtf(var + 1e-5f) * g_ln + b_ln;
                if (e == 0)      { kar = y;          zc[t] = zbr + 0.5f * h * y; }
                else if (e == 1) { kar += 2.f * y;   zc[t] = zbr + 0.5f * h * y; }
                else if (e == 2) { kar += 2.f * y;   zc[t] = zbr + h * y; }
                else {
                    kar += y;
                    float zn = zbr + (h * (1.f / 6.f)) * kar;
                    zt_out[b * 12800 + (step + 1) * 64 + t] = zn;
                    zd_out[b * 12736 + step * 64 + t] = (zn - zbr) / h;  // as reference
                    zbr = zn; zc[t] = zn;
                }
            }
            __syncthreads();
        }
    }
}

// ---------------------------------------------------------------------------
// Kernel 2.5: weight transpose + bf16 pack for the decoder GEMMs (unchanged).
// ---------------------------------------------------------------------------
__global__ __launch_bounds__(256) void wt_kernel(
    const void* __restrict__ w1, const void* __restrict__ w2,
    const void* __restrict__ w3, const void* __restrict__ tvec,
    u16* __restrict__ wt1, u16* __restrict__ wt2, u16* __restrict__ wt3)
{
    __shared__ u16 tile[64][65];
    const bool m = detect_f32(tvec);
    const int b = blockIdx.x;
    const void* src; u16* dst; int K, kt, nt0;
    if (b < 8)       { src = w1; dst = wt1; K = 64;  kt = 0;          nt0 = b; }
    else if (b < 72) { src = w2; dst = wt2; K = 512; kt = (b-8) >> 3; nt0 = (b-8) & 7; }
    else             { src = w3; dst = wt3; K = 512; kt = (b-72) >> 3; nt0 = (b-72) & 7; }
    const int k0 = kt * 64, n0 = nt0 * 64;
    const int t = threadIdx.x;
    #pragma unroll
    for (int i = 0; i < 16; ++i) {
        int idx = t + 256 * i;                // 4096 elements per 64x64 tile
        int r = idx >> 6, c = idx & 63;       // r = k offset, c = n offset
        tile[r][c] = f2bf(loadf(src, (long)(k0 + r) * 512 + n0 + c, m));
    }
    __syncthreads();
    #pragma unroll
    for (int i = 0; i < 16; ++i) {
        int idx = t + 256 * i;
        int c = idx >> 6, r = idx & 63;       // c = n offset, r = k offset
        int pk = ((r >> 3) & 3) * 16 + ((r >> 5) & 1) * 8 + (r & 7);
        dst[(long)(n0 + c) * K + k0 + pk] = tile[r][c];
    }
}

// ---------------------------------------------------------------------------
// Kernel 3: decoder — bf16 MFMA GEMM chain (unchanged, verified).
// ---------------------------------------------------------------------------
template<int K, int INROWB, bool RELU, bool TOLDS>
__device__ __forceinline__ void dec_layer(
    const u16* __restrict__ WT, const float* __restrict__ bl,
    const u16* Xin, u16* Xout, float* __restrict__ gout,
    long r0, int w, int lm, int lh)
{
    f32x4 acc[8][4];
    #pragma unroll
    for (int a = 0; a < 8; ++a)
        #pragma unroll
        for (int b = 0; b < 4; ++b) { f32x4 z4 = {0.f, 0.f, 0.f, 0.f}; acc[a][b] = z4; }

    #pragma unroll 1
    for (int kk2 = 0; kk2 < K / 64; ++kk2) {
        #pragma unroll
        for (int half = 0; half < 2; ++half) {
            const int kb = kk2 * 64 + half * 32 + lh * 8;   // logical k base
            bf8v bfr[4];
            #pragma unroll
            for (int mt = 0; mt < 4; ++mt) {
                int mr = mt * 16 + lm;
                int byte = mr * INROWB + kb * 2;
                bfr[mt] = *(const bf8v*)((const char*)Xin + (byte ^ ((mr & 7) << 4)));
            }
            bf8v afr[8];
            #pragma unroll
            for (int nt = 0; nt < 8; ++nt) {
                int n = w * 128 + nt * 16 + lm;
                afr[nt] = *(const bf8v*)&WT[(long)n * K + kk2 * 64 + lh * 16 + half * 8];
            }
            #pragma unroll
            for (int nt = 0; nt < 8; ++nt)
                #pragma unroll
                for (int mt = 0; mt < 4; ++mt)
                    acc[nt][mt] = __builtin_amdgcn_mfma_f32_16x16x32_bf16(
                        afr[nt], bfr[mt], acc[nt][mt], 0, 0, 0);
        }
    }
    __syncthreads();   // all Xin reads complete (required before in-place overwrite)

    // epilogue: bias (+relu), then bf16->LDS (8B packed) or fp32->global
    #pragma unroll
    for (int nt = 0; nt < 8; ++nt) {
        const int n0 = w * 128 + nt * 16 + lh * 4;     // D row = lh*4 + reg (m89)
        f32x4 bv = *(const f32x4*)&bl[n0];
        #pragma unroll
        for (int mt = 0; mt < 4; ++mt) {
            f32x4 v = acc[nt][mt];
            v.x += bv.x; v.y += bv.y; v.z += bv.z; v.w += bv.w;
            if (RELU) {
                v.x = fmaxf(v.x, 0.f); v.y = fmaxf(v.y, 0.f);
                v.z = fmaxf(v.z, 0.f); v.w = fmaxf(v.w, 0.f);
            }
            const int mr = mt * 16 + lm;               // D col = lane&15 (m89)
            if (TOLDS) {
                bf4v h;
                h.x = (short)f2bf(v.x); h.y = (short)f2bf(v.y);
                h.z = (short)f2bf(v.z); h.w = (short)f2bf(v.w);
                int byte = mr * 1024 + n0 * 2;
                *(bf4v*)((char*)Xout + (byte ^ ((mr & 7) << 4))) = h;
            } else {
                *(f32x4*)&gout[(r0 + mr) * 512 + n0] = v;
            }
        }
    }
    __syncthreads();   // Xout visible to all waves
}

__global__ __launch_bounds__(256, 2) void dec_kernel(
    const float* __restrict__ zt, const void* __restrict__ tvec,
    const u16* __restrict__ wt1, const u16* __restrict__ wt2,
    const u16* __restrict__ wt3,
    const void* __restrict__ b1, const void* __restrict__ b2,
    const void* __restrict__ b3,
    float* __restrict__ xhat)
{
    __shared__ __align__(16) u16 X0[64 * 64];     // z tile, bf16, row=128B, swizzled
    __shared__ __align__(16) u16 X1[64 * 512];    // activation, row=1024B, swizzled
    __shared__ __align__(16) float bl1[512], bl2[512], bl3[512];

    const bool m = detect_f32(tvec);
    const int t = threadIdx.x;
    const int l = t & 63, w = t >> 6;
    const int lm = l & 15, lh = l >> 4;
    const long r0 = (long)blockIdx.x * 64;

    // stage biases to LDS (fp32)
    bl1[t] = loadf(b1, t, m); bl1[t + 256] = loadf(b1, t + 256, m);
    bl2[t] = loadf(b2, t, m); bl2[t + 256] = loadf(b2, t + 256, m);
    bl3[t] = loadf(b3, t, m); bl3[t + 256] = loadf(b3, t + 256, m);

    // stage z rows (fp32 global) -> X0 bf16, swizzled
    {
        const int mrow = t >> 2;
        const int c0 = (t & 3) * 16;
        const float* zr = zt + (r0 + mrow) * 64 + c0;
        #pragma unroll
        for (int j = 0; j < 4; ++j) {
            float4 v = *(const float4*)(zr + 4 * j);
            bf4v h;
            h.x = (short)f2bf(v.x); h.y = (short)f2bf(v.y);
            h.z = (short)f2bf(v.z); h.w = (short)f2bf(v.w);
            int byte = mrow * 128 + (c0 + 4 * j) * 2;
            *(bf4v*)((char*)X0 + (byte ^ ((mrow & 7) << 4))) = h;
        }
    }
    __syncthreads();

    dec_layer< 64,  128, true,  true >(wt1, bl1, X0, X1, nullptr, r0, w, lm, lh);
    dec_layer<512, 1024, true,  true >(wt2, bl2, X1, X1, nullptr, r0, w, lm, lh);
    dec_layer<512, 1024, false, false>(wt3, bl3, X1, nullptr, xhat, r0, w, lm, lh);
}

// ---------------------------------------------------------------------------
extern "C" void kernel_launch(void* const* d_in, const int* in_sizes, int n_in,
                              void* d_out, int out_size, void* d_ws, size_t ws_size,
                              hipStream_t stream)
{
    float* out = (float*)d_out;
    float* z0f = (float*)d_ws;                                   // 64 KB
    u16* wt1 = (u16*)((char*)d_ws + 65536);                      // 512x64  bf16 = 64 KB
    u16* wt2 = (u16*)((char*)d_ws + 65536 + 65536);              // 512x512 bf16 = 512 KB
    u16* wt3 = (u16*)((char*)d_ws + 65536 + 65536 + 524288);     // 512x512 bf16 = 512 KB

    // decoder weight transpose/pack (independent of enc/ode)
    wt_kernel<<<136, 256, 0, stream>>>(
        d_in[21], d_in[23], d_in[25], d_in[1], wt1, wt2, wt3);

    enc_kernel<<<128, 512, 0, stream>>>(
        d_in[0], d_in[1], d_in[2], d_in[3], d_in[4], d_in[5], d_in[6],
        d_in[7], d_in[8], d_in[9], d_in[10], d_in[11], d_in[12],
        out, z0f);

    ode_kernel<<<256, 256, 0, stream>>>(
        d_in[1], d_in[13], d_in[14], d_in[15], d_in[16],
        d_in[17], d_in[18], d_in[19], d_in[20], z0f,
        out + ZT_OFF, out + ZD_OFF);

    dec_kernel<<<800, 256, 0, stream>>>(
        out + ZT_OFF, d_in[1], wt1, wt2, wt3,
        d_in[22], d_in[24], d_in[26], out);
}